// Round 1
// baseline (979.678 us; speedup 1.0000x reference)
//
#include <hip/hip_runtime.h>

#define SEQ 4096
#define DMODEL 1024
#define HEADNUM 16
#define DHEAD 64

typedef __attribute__((ext_vector_type(8))) short short8;
typedef __attribute__((ext_vector_type(4))) float f32x4;

__device__ __forceinline__ short f2bf(float f) {
    unsigned u = __float_as_uint(f);
    u = (u + 0x7fffu + ((u >> 16) & 1u)) >> 16;
    return (short)u;
}

__device__ __forceinline__ short8 cvt8(const float4 a, const float4 b) {
    short8 r;
    r[0] = f2bf(a.x); r[1] = f2bf(a.y); r[2] = f2bf(a.z); r[3] = f2bf(a.w);
    r[4] = f2bf(b.x); r[5] = f2bf(b.y); r[6] = f2bf(b.z); r[7] = f2bf(b.w);
    return r;
}

// ---------------------------------------------------------------------------
// Transpose + cast weights: W [H][DMODEL][DHEAD] f32  ->  WT [H][DHEAD][DMODEL] bf16
// ---------------------------------------------------------------------------
__global__ __launch_bounds__(256) void wtrans_kernel(const float* __restrict__ W,
                                                     short* __restrict__ WT) {
    int idx = blockIdx.x * 256 + threadIdx.x;
    if (idx >= HEADNUM * DHEAD * DMODEL) return;
    int d = idx & (DMODEL - 1);
    int t = idx >> 10;
    int n = t & (DHEAD - 1);
    int h = t >> 6;
    WT[idx] = f2bf(W[(h * DMODEL + d) * DHEAD + n]);
}

// ---------------------------------------------------------------------------
// Per-head projection GEMM: out[h] = in[4096,1024] @ WT[h]^T   (N = 64)
// which==0 -> qh [h][s][64], which==1 -> kh [h][s][64], which==2 -> vt [h][v][s]
// ---------------------------------------------------------------------------
__global__ __launch_bounds__(256) void proj_kernel(
    const float* __restrict__ q, const float* __restrict__ k, const float* __restrict__ v,
    const short* __restrict__ WqT, const short* __restrict__ WkT, const short* __restrict__ WvT,
    short* __restrict__ qh, short* __restrict__ kh, short* __restrict__ vt) {
    int h = blockIdx.y;
    int which = blockIdx.z;
    const float* in;
    const short* WT;
    if (which == 0)      { in = q; WT = WqT; }
    else if (which == 1) { in = k; WT = WkT; }
    else                 { in = v; WT = WvT; }
    WT += h * DHEAD * DMODEL;

    int lane = threadIdx.x & 63;
    int wv = threadIdx.x >> 6;
    int l15 = lane & 15;
    int kgrp = (lane >> 4) * 8;
    int srow = blockIdx.x * 64 + wv * 16 + l15;

    f32x4 acc[4];
#pragma unroll
    for (int t = 0; t < 4; ++t) acc[t] = (f32x4){0.f, 0.f, 0.f, 0.f};

    for (int d0 = 0; d0 < DMODEL; d0 += 32) {
        const float* ap = &in[srow * DMODEL + d0 + kgrp];
        float4 a0 = *(const float4*)(ap);
        float4 a1 = *(const float4*)(ap + 4);
        short8 a = cvt8(a0, a1);
#pragma unroll
        for (int t = 0; t < 4; ++t) {
            short8 b = *(const short8*)(&WT[(t * 16 + l15) * DMODEL + d0 + kgrp]);
            acc[t] = __builtin_amdgcn_mfma_f32_16x16x32_bf16(a, b, acc[t], 0, 0, 0);
        }
    }

    int rbase = blockIdx.x * 64 + wv * 16 + (lane >> 4) * 4;
    if (which < 2) {
        short* out = (which == 0 ? qh : kh) + h * SEQ * DHEAD;
#pragma unroll
        for (int t = 0; t < 4; ++t)
#pragma unroll
            for (int r = 0; r < 4; ++r)
                out[(rbase + r) * DHEAD + t * 16 + l15] = f2bf(acc[t][r]);
    } else {
        short* out = vt + h * DHEAD * SEQ;
#pragma unroll
        for (int t = 0; t < 4; ++t)
#pragma unroll
            for (int r = 0; r < 4; ++r)
                out[(t * 16 + l15) * SEQ + rbase + r] = f2bf(acc[t][r]);
    }
}

// ---------------------------------------------------------------------------
// Flash attention per head. Block = 64 q-rows (4 waves x 16), loop kv in 64-key
// tiles. qh/kh [h][s][64] bf16, vt [h][v][s] bf16. Output head_cat bf16
// [s][HEADNUM*DHEAD].
// ---------------------------------------------------------------------------
__global__ __launch_bounds__(256) void attn_kernel(
    const short* __restrict__ qh, const short* __restrict__ kh,
    const short* __restrict__ vt, short* __restrict__ hc) {
    int h = blockIdx.y;
    const short* qh_h = qh + h * SEQ * DHEAD;
    const short* kh_h = kh + h * SEQ * DHEAD;
    const short* vt_h = vt + h * DHEAD * SEQ;

    int lane = threadIdx.x & 63;
    int wv = threadIdx.x >> 6;
    int l15 = lane & 15;
    int kgrp = (lane >> 4) * 8;
    int qbase = blockIdx.x * 64 + wv * 16;

    __shared__ short p_lds[4][16][64];

    short8 aq[2];
    aq[0] = *(const short8*)(&qh_h[(qbase + l15) * DHEAD + 0 + kgrp]);
    aq[1] = *(const short8*)(&qh_h[(qbase + l15) * DHEAD + 32 + kgrp]);

    float m[4], ls[4];
    f32x4 oacc[4];
#pragma unroll
    for (int r = 0; r < 4; ++r) { m[r] = -1e30f; ls[r] = 0.f; }
#pragma unroll
    for (int t = 0; t < 4; ++t) oacc[t] = (f32x4){0.f, 0.f, 0.f, 0.f};

    for (int kb = 0; kb < SEQ; kb += 64) {
        // ---- S = Q K^T (scaled) ----
        f32x4 sacc[4];
#pragma unroll
        for (int t = 0; t < 4; ++t) sacc[t] = (f32x4){0.f, 0.f, 0.f, 0.f};
#pragma unroll
        for (int t = 0; t < 4; ++t) {
#pragma unroll
            for (int c = 0; c < 2; ++c) {
                short8 bk = *(const short8*)(&kh_h[(kb + t * 16 + l15) * DHEAD + c * 32 + kgrp]);
                sacc[t] = __builtin_amdgcn_mfma_f32_16x16x32_bf16(aq[c], bk, sacc[t], 0, 0, 0);
            }
        }
        float p[4][4];
#pragma unroll
        for (int t = 0; t < 4; ++t)
#pragma unroll
            for (int r = 0; r < 4; ++r) p[t][r] = sacc[t][r] * 0.125f;

        // ---- online softmax (rows live in (lane>>4)*4+r; reduce over l&15) ----
#pragma unroll
        for (int r = 0; r < 4; ++r) {
            float mx = fmaxf(fmaxf(p[0][r], p[1][r]), fmaxf(p[2][r], p[3][r]));
#pragma unroll
            for (int msk = 1; msk < 16; msk <<= 1) mx = fmaxf(mx, __shfl_xor(mx, msk));
            float nmr = fmaxf(m[r], mx);
            float al = __expf(m[r] - nmr);
            float sum = 0.f;
#pragma unroll
            for (int t = 0; t < 4; ++t) {
                float e = __expf(p[t][r] - nmr);
                p[t][r] = e;
                sum += e;
            }
#pragma unroll
            for (int msk = 1; msk < 16; msk <<= 1) sum += __shfl_xor(sum, msk);
            ls[r] = ls[r] * al + sum;
            m[r] = nmr;
#pragma unroll
            for (int t = 0; t < 4; ++t) oacc[t][r] *= al;
        }

        // ---- P: D-layout -> A-fragment layout via per-wave LDS buffer ----
#pragma unroll
        for (int t = 0; t < 4; ++t)
#pragma unroll
            for (int r = 0; r < 4; ++r)
                p_lds[wv][(lane >> 4) * 4 + r][t * 16 + l15] = f2bf(p[t][r]);
        __syncthreads();
        short8 pa0 = *(const short8*)(&p_lds[wv][l15][kgrp]);
        short8 pa1 = *(const short8*)(&p_lds[wv][l15][32 + kgrp]);

        // ---- O += P V ----
#pragma unroll
        for (int t = 0; t < 4; ++t) {
            const short* vp = &vt_h[(t * 16 + l15) * SEQ + kb];
            short8 bv0 = *(const short8*)(vp + kgrp);
            short8 bv1 = *(const short8*)(vp + 32 + kgrp);
            oacc[t] = __builtin_amdgcn_mfma_f32_16x16x32_bf16(pa0, bv0, oacc[t], 0, 0, 0);
            oacc[t] = __builtin_amdgcn_mfma_f32_16x16x32_bf16(pa1, bv1, oacc[t], 0, 0, 0);
        }
        __syncthreads();
    }

    // ---- normalize + write head_cat ----
#pragma unroll
    for (int t = 0; t < 4; ++t)
#pragma unroll
        for (int r = 0; r < 4; ++r) {
            float ov = oacc[t][r] / ls[r];
            int srow = qbase + (lane >> 4) * 4 + r;
            hc[srow * (HEADNUM * DHEAD) + h * DHEAD + t * 16 + l15] = f2bf(ov);
        }
}

// ---------------------------------------------------------------------------
// Output GEMM: out[4096,1024] = hc[4096,1024](bf16) @ Wo^T   (Wo [o][i] f32)
// ---------------------------------------------------------------------------
__global__ __launch_bounds__(256) void ogemm_kernel(
    const short* __restrict__ hc, const float* __restrict__ Wo,
    float* __restrict__ out) {
    int lane = threadIdx.x & 63;
    int wv = threadIdx.x >> 6;
    int l15 = lane & 15;
    int kgrp = (lane >> 4) * 8;
    int sbase = blockIdx.x * 64 + wv * 16;
    int obase = blockIdx.y * 64;

    f32x4 acc[4];
#pragma unroll
    for (int t = 0; t < 4; ++t) acc[t] = (f32x4){0.f, 0.f, 0.f, 0.f};

    for (int d0 = 0; d0 < DMODEL; d0 += 32) {
        short8 a = *(const short8*)(&hc[(sbase + l15) * DMODEL + d0 + kgrp]);
#pragma unroll
        for (int t = 0; t < 4; ++t) {
            const float* wp = &Wo[(obase + t * 16 + l15) * DMODEL + d0 + kgrp];
            float4 b0 = *(const float4*)(wp);
            float4 b1 = *(const float4*)(wp + 4);
            short8 b = cvt8(b0, b1);
            acc[t] = __builtin_amdgcn_mfma_f32_16x16x32_bf16(a, b, acc[t], 0, 0, 0);
        }
    }
#pragma unroll
    for (int t = 0; t < 4; ++t)
#pragma unroll
        for (int r = 0; r < 4; ++r)
            out[(sbase + (lane >> 4) * 4 + r) * DMODEL + obase + t * 16 + l15] = acc[t][r];
}

// ---------------------------------------------------------------------------
extern "C" void kernel_launch(void* const* d_in, const int* in_sizes, int n_in,
                              void* d_out, int out_size, void* d_ws, size_t ws_size,
                              hipStream_t stream) {
    const float* q  = (const float*)d_in[0];
    const float* k  = (const float*)d_in[1];
    const float* v  = (const float*)d_in[2];
    const float* Wq = (const float*)d_in[3];
    const float* Wk = (const float*)d_in[4];
    const float* Wv = (const float*)d_in[5];
    const float* Wo = (const float*)d_in[6];
    float* out = (float*)d_out;

    char* ws = (char*)d_ws;
    const size_t MB = 1u << 20;
    short* WqT = (short*)(ws + 0 * MB);   // 2 MB
    short* WkT = (short*)(ws + 2 * MB);   // 2 MB
    short* WvT = (short*)(ws + 4 * MB);   // 2 MB
    short* qh  = (short*)(ws + 6 * MB);   // 8 MB
    short* kh  = (short*)(ws + 14 * MB);  // 8 MB
    short* vt  = (short*)(ws + 22 * MB);  // 8 MB
    short* hc  = (short*)(ws + 30 * MB);  // 8 MB

    int wn = HEADNUM * DHEAD * DMODEL;  // 1048576
    wtrans_kernel<<<dim3((wn + 255) / 256), 256, 0, stream>>>(Wq, WqT);
    wtrans_kernel<<<dim3((wn + 255) / 256), 256, 0, stream>>>(Wk, WkT);
    wtrans_kernel<<<dim3((wn + 255) / 256), 256, 0, stream>>>(Wv, WvT);

    proj_kernel<<<dim3(SEQ / 64, HEADNUM, 3), 256, 0, stream>>>(
        q, k, v, WqT, WkT, WvT, qh, kh, vt);

    attn_kernel<<<dim3(SEQ / 64, HEADNUM), 256, 0, stream>>>(qh, kh, vt, hc);

    ogemm_kernel<<<dim3(SEQ / 64, DMODEL / 64), 256, 0, stream>>>(hc, Wo, out);
}

// Round 2
// 529.212 us; speedup vs baseline: 1.8512x; 1.8512x over previous
//
#include <hip/hip_runtime.h>

#define SEQ 4096
#define DMODEL 1024
#define HEADNUM 16
#define DHEAD 64

typedef __attribute__((ext_vector_type(8))) short short8;
typedef __attribute__((ext_vector_type(4))) float f32x4;

__device__ __forceinline__ short f2bf(float f) {
    unsigned u = __float_as_uint(f);
    u = (u + 0x7fffu + ((u >> 16) & 1u)) >> 16;
    return (short)u;
}

__device__ __forceinline__ short8 cvt8(const float4 a, const float4 b) {
    short8 r;
    r[0] = f2bf(a.x); r[1] = f2bf(a.y); r[2] = f2bf(a.z); r[3] = f2bf(a.w);
    r[4] = f2bf(b.x); r[5] = f2bf(b.y); r[6] = f2bf(b.z); r[7] = f2bf(b.w);
    return r;
}

__device__ __forceinline__ void gld16(const void* g, void* l) {
    __builtin_amdgcn_global_load_lds(
        (const __attribute__((address_space(1))) void*)g,
        (__attribute__((address_space(3))) void*)l, 16, 0, 0);
}

// ---------------------------------------------------------------------------
// Transpose + cast weights: W [H][DMODEL][DHEAD] f32 -> WT [H][DHEAD][DMODEL] bf16
// ---------------------------------------------------------------------------
__global__ __launch_bounds__(256) void wtrans_kernel(const float* __restrict__ W,
                                                     short* __restrict__ WT) {
    int idx = blockIdx.x * 256 + threadIdx.x;
    if (idx >= HEADNUM * DHEAD * DMODEL) return;
    int d = idx & (DMODEL - 1);
    int t = idx >> 10;
    int n = t & (DHEAD - 1);
    int h = t >> 6;
    WT[idx] = f2bf(W[(h * DMODEL + d) * DHEAD + n]);
}

// ---------------------------------------------------------------------------
// Plain cast f32 -> bf16, vectorized 8/thread
// ---------------------------------------------------------------------------
__global__ __launch_bounds__(256) void cast_bf16_kernel(const float* __restrict__ in,
                                                        short* __restrict__ out, int n8) {
    int i = blockIdx.x * 256 + threadIdx.x;
    if (i >= n8) return;
    const float4* p = (const float4*)(in + i * 8);
    *(short8*)(out + i * 8) = cvt8(p[0], p[1]);
}

// ---------------------------------------------------------------------------
// Per-head projection GEMM: out[h] = in[4096,1024] @ WT[h]^T   (N = 64)
// which==0 -> qh [h][s][64], which==1 -> kh [h][s][64], which==2 -> vt [h][v][s]
// ---------------------------------------------------------------------------
__global__ __launch_bounds__(256) void proj_kernel(
    const float* __restrict__ qf, const float* __restrict__ kf, const float* __restrict__ vf,
    const short* __restrict__ qb, const short* __restrict__ kb2, const short* __restrict__ vb2,
    const short* __restrict__ WqT, const short* __restrict__ WkT, const short* __restrict__ WvT,
    short* __restrict__ qh, short* __restrict__ kh, short* __restrict__ vt, int use_pre) {
    int h = blockIdx.y;
    int which = blockIdx.z;
    const float* inf;
    const short* inb;
    const short* WT;
    if (which == 0)      { inf = qf; inb = qb;  WT = WqT; }
    else if (which == 1) { inf = kf; inb = kb2; WT = WkT; }
    else                 { inf = vf; inb = vb2; WT = WvT; }
    WT += h * DHEAD * DMODEL;

    int lane = threadIdx.x & 63;
    int wv = threadIdx.x >> 6;
    int l15 = lane & 15;
    int kgrp = (lane >> 4) * 8;
    int srow = blockIdx.x * 64 + wv * 16 + l15;

    f32x4 acc[4];
#pragma unroll
    for (int t = 0; t < 4; ++t) acc[t] = (f32x4){0.f, 0.f, 0.f, 0.f};

    if (use_pre) {
        for (int d0 = 0; d0 < DMODEL; d0 += 32) {
            short8 a = *(const short8*)(&inb[srow * DMODEL + d0 + kgrp]);
#pragma unroll
            for (int t = 0; t < 4; ++t) {
                short8 b = *(const short8*)(&WT[(t * 16 + l15) * DMODEL + d0 + kgrp]);
                acc[t] = __builtin_amdgcn_mfma_f32_16x16x32_bf16(a, b, acc[t], 0, 0, 0);
            }
        }
    } else {
        for (int d0 = 0; d0 < DMODEL; d0 += 32) {
            const float* ap = &inf[srow * DMODEL + d0 + kgrp];
            short8 a = cvt8(((const float4*)ap)[0], ((const float4*)ap)[1]);
#pragma unroll
            for (int t = 0; t < 4; ++t) {
                short8 b = *(const short8*)(&WT[(t * 16 + l15) * DMODEL + d0 + kgrp]);
                acc[t] = __builtin_amdgcn_mfma_f32_16x16x32_bf16(a, b, acc[t], 0, 0, 0);
            }
        }
    }

    int rbase = blockIdx.x * 64 + wv * 16 + (lane >> 4) * 4;
    if (which < 2) {
        short* out = (which == 0 ? qh : kh) + h * SEQ * DHEAD;
#pragma unroll
        for (int t = 0; t < 4; ++t)
#pragma unroll
            for (int r = 0; r < 4; ++r)
                out[(rbase + r) * DHEAD + t * 16 + l15] = f2bf(acc[t][r]);
    } else {
        short* out = vt + h * DHEAD * SEQ;
#pragma unroll
        for (int t = 0; t < 4; ++t)
#pragma unroll
            for (int r = 0; r < 4; ++r)
                out[(t * 16 + l15) * SEQ + rbase + r] = f2bf(acc[t][r]);
    }
}

// ---------------------------------------------------------------------------
// Flash attention per head. 64 q-rows/block (4 waves x 16). K/V tiles staged in
// LDS (double-buffered, XOR-swizzled via pre-swizzled global source, prefetched
// with global_load_lds). One barrier per tile; P transpose is wave-private.
// ---------------------------------------------------------------------------
__global__ __launch_bounds__(256) void attn_kernel(
    const short* __restrict__ qh, const short* __restrict__ kh,
    const short* __restrict__ vt, short* __restrict__ hc) {
    // XCD swizzle: 1024 blocks, 8 XCDs -> each XCD owns 128 consecutive wgs = 2 heads
    int wg = ((blockIdx.x & 7) << 7) | (blockIdx.x >> 3);
    int h = wg >> 6;
    int qblk = wg & 63;

    const short* qh_h = qh + h * SEQ * DHEAD;
    const short* kh_h = kh + h * SEQ * DHEAD;
    const short* vt_h = vt + h * DHEAD * SEQ;

    int tid = threadIdx.x;
    int lane = tid & 63;
    int wv = tid >> 6;
    int l15 = lane & 15;
    int hi16 = (lane >> 4) * 16;  // byte offset of k-group within a 64-elem row half
    int qbase = qblk * 64 + wv * 16;

    __shared__ short kbuf[2][64 * 64];
    __shared__ short vbuf[2][64 * 64];
    __shared__ short p_lds[4][16 * 64];

    // Q fragments (held in registers for the whole sweep)
    const short* qp = &qh_h[(qbase + l15) * DHEAD + (lane >> 4) * 8];
    short8 aq0 = *(const short8*)(qp);
    short8 aq1 = *(const short8*)(qp + 32);

    // staging offsets: thread covers 16B chunks at LDS j0/j1; source pre-swizzled
    int j0 = tid * 16;
    int j1 = j0 + 4096;
    int row0 = j0 >> 7, row1 = j1 >> 7;
    int sw0 = (row0 & 7) << 4, sw1 = (row1 & 7) << 4;
    int ksrc0 = j0 ^ sw0;                                   // K tile is contiguous
    int ksrc1 = j1 ^ sw1;
    int vsrc0 = row0 * (SEQ * 2) + ((j0 & 127) ^ sw0);      // V rows stride SEQ
    int vsrc1 = row1 * (SEQ * 2) + ((j1 & 127) ^ sw1);

#define STAGE(bi, kbase)                                                          \
    {                                                                             \
        gld16((const char*)kh_h + (kbase) * 128 + ksrc0, (char*)kbuf[bi] + j0);   \
        gld16((const char*)kh_h + (kbase) * 128 + ksrc1, (char*)kbuf[bi] + j1);   \
        gld16((const char*)vt_h + (kbase) * 2 + vsrc0, (char*)vbuf[bi] + j0);     \
        gld16((const char*)vt_h + (kbase) * 2 + vsrc1, (char*)vbuf[bi] + j1);     \
    }

    float m[4], ls[4];
    f32x4 oacc[4];
#pragma unroll
    for (int r = 0; r < 4; ++r) { m[r] = -1e30f; ls[r] = 0.f; }
#pragma unroll
    for (int t = 0; t < 4; ++t) oacc[t] = (f32x4){0.f, 0.f, 0.f, 0.f};

    STAGE(0, 0);
    int cur = 0;

    for (int kb = 0; kb < SEQ; kb += 64) {
        __syncthreads();  // implicit vmcnt(0): stage(kb) complete, all waves synced
        if (kb + 64 < SEQ) STAGE(cur ^ 1, kb + 64);

        const char* kp = (const char*)kbuf[cur];
        const char* vp = (const char*)vbuf[cur];

        // ---- S = Q K^T (scaled) ----
        float p[4][4];
#pragma unroll
        for (int t = 0; t < 4; ++t) {
            f32x4 sacc = (f32x4){0.f, 0.f, 0.f, 0.f};
            int row = t * 16 + l15;
            int sw = (row & 7) << 4;
            short8 bk0 = *(const short8*)(kp + row * 128 + (hi16 ^ sw));
            short8 bk1 = *(const short8*)(kp + row * 128 + ((64 + hi16) ^ sw));
            sacc = __builtin_amdgcn_mfma_f32_16x16x32_bf16(aq0, bk0, sacc, 0, 0, 0);
            sacc = __builtin_amdgcn_mfma_f32_16x16x32_bf16(aq1, bk1, sacc, 0, 0, 0);
#pragma unroll
            for (int r = 0; r < 4; ++r) p[t][r] = sacc[r] * 0.125f;
        }

        // ---- online softmax (rows = (lane>>4)*4+r; reduce over lane&15) ----
#pragma unroll
        for (int r = 0; r < 4; ++r) {
            float mx = fmaxf(fmaxf(p[0][r], p[1][r]), fmaxf(p[2][r], p[3][r]));
#pragma unroll
            for (int msk = 1; msk < 16; msk <<= 1) mx = fmaxf(mx, __shfl_xor(mx, msk));
            float nmr = fmaxf(m[r], mx);
            float al = __expf(m[r] - nmr);
            float sum = 0.f;
#pragma unroll
            for (int t = 0; t < 4; ++t) {
                float e = __expf(p[t][r] - nmr);
                p[t][r] = e;
                sum += e;
            }
#pragma unroll
            for (int msk = 1; msk < 16; msk <<= 1) sum += __shfl_xor(sum, msk);
            ls[r] = ls[r] * al + sum;
            m[r] = nmr;
#pragma unroll
            for (int t = 0; t < 4; ++t) oacc[t][r] *= al;
        }

        // ---- P: D-layout -> A-fragment via wave-private swizzled LDS ----
        char* pw = (char*)p_lds[wv];
#pragma unroll
        for (int r = 0; r < 4; ++r) {
            int prow = (lane >> 4) * 4 + r;
            int psw = (prow & 7) << 4;
            char* base = pw + prow * 128;
#pragma unroll
            for (int t = 0; t < 4; ++t)
                *(short*)(base + (((t * 16 + l15) * 2) ^ psw)) = f2bf(p[t][r]);
        }
        asm volatile("s_waitcnt lgkmcnt(0)" ::: "memory");  // wave-private: no barrier
        {
            int asw = (l15 & 7) << 4;
            const char* pr = pw + l15 * 128;
            short8 pa0 = *(const short8*)(pr + (hi16 ^ asw));
            short8 pa1 = *(const short8*)(pr + ((64 + hi16) ^ asw));

            // ---- O += P V ----
#pragma unroll
            for (int t = 0; t < 4; ++t) {
                int row = t * 16 + l15;
                int sw = (row & 7) << 4;
                short8 bv0 = *(const short8*)(vp + row * 128 + (hi16 ^ sw));
                short8 bv1 = *(const short8*)(vp + row * 128 + ((64 + hi16) ^ sw));
                oacc[t] = __builtin_amdgcn_mfma_f32_16x16x32_bf16(pa0, bv0, oacc[t], 0, 0, 0);
                oacc[t] = __builtin_amdgcn_mfma_f32_16x16x32_bf16(pa1, bv1, oacc[t], 0, 0, 0);
            }
        }
        cur ^= 1;
    }
#undef STAGE

    // ---- normalize + write head_cat ----
#pragma unroll
    for (int t = 0; t < 4; ++t)
#pragma unroll
        for (int r = 0; r < 4; ++r) {
            float ov = oacc[t][r] / ls[r];
            int srow = qbase + (lane >> 4) * 4 + r;
            hc[srow * (HEADNUM * DHEAD) + h * DHEAD + t * 16 + l15] = f2bf(ov);
        }
}

// ---------------------------------------------------------------------------
// Output GEMM: out[4096,1024] = hc[4096,1024](bf16) @ Wo^T   (Wo [o][i])
// ---------------------------------------------------------------------------
__global__ __launch_bounds__(256) void ogemm_kernel(
    const short* __restrict__ hc, const float* __restrict__ Wo,
    const short* __restrict__ Wob, float* __restrict__ out, int use_pre) {
    int lane = threadIdx.x & 63;
    int wv = threadIdx.x >> 6;
    int l15 = lane & 15;
    int kgrp = (lane >> 4) * 8;
    int sbase = blockIdx.x * 64 + wv * 16;
    int obase = blockIdx.y * 64;

    f32x4 acc[4];
#pragma unroll
    for (int t = 0; t < 4; ++t) acc[t] = (f32x4){0.f, 0.f, 0.f, 0.f};

    if (use_pre) {
        for (int d0 = 0; d0 < DMODEL; d0 += 32) {
            short8 a = *(const short8*)(&hc[(sbase + l15) * DMODEL + d0 + kgrp]);
#pragma unroll
            for (int t = 0; t < 4; ++t) {
                short8 b = *(const short8*)(&Wob[(obase + t * 16 + l15) * DMODEL + d0 + kgrp]);
                acc[t] = __builtin_amdgcn_mfma_f32_16x16x32_bf16(a, b, acc[t], 0, 0, 0);
            }
        }
    } else {
        for (int d0 = 0; d0 < DMODEL; d0 += 32) {
            short8 a = *(const short8*)(&hc[(sbase + l15) * DMODEL + d0 + kgrp]);
#pragma unroll
            for (int t = 0; t < 4; ++t) {
                const float* wp = &Wo[(obase + t * 16 + l15) * DMODEL + d0 + kgrp];
                short8 b = cvt8(((const float4*)wp)[0], ((const float4*)wp)[1]);
                acc[t] = __builtin_amdgcn_mfma_f32_16x16x32_bf16(a, b, acc[t], 0, 0, 0);
            }
        }
    }
#pragma unroll
    for (int t = 0; t < 4; ++t)
#pragma unroll
        for (int r = 0; r < 4; ++r)
            out[(sbase + (lane >> 4) * 4 + r) * DMODEL + obase + t * 16 + l15] = acc[t][r];
}

// ---------------------------------------------------------------------------
extern "C" void kernel_launch(void* const* d_in, const int* in_sizes, int n_in,
                              void* d_out, int out_size, void* d_ws, size_t ws_size,
                              hipStream_t stream) {
    const float* q  = (const float*)d_in[0];
    const float* k  = (const float*)d_in[1];
    const float* v  = (const float*)d_in[2];
    const float* Wq = (const float*)d_in[3];
    const float* Wk = (const float*)d_in[4];
    const float* Wv = (const float*)d_in[5];
    const float* Wo = (const float*)d_in[6];
    float* out = (float*)d_out;

    char* ws = (char*)d_ws;
    const size_t MB = 1u << 20;
    short* WqT = (short*)(ws + 0 * MB);   // 2 MB
    short* WkT = (short*)(ws + 2 * MB);   // 2 MB
    short* WvT = (short*)(ws + 4 * MB);   // 2 MB
    short* qh  = (short*)(ws + 6 * MB);   // 8 MB
    short* kh  = (short*)(ws + 14 * MB);  // 8 MB
    short* vt  = (short*)(ws + 22 * MB);  // 8 MB
    short* hc  = (short*)(ws + 30 * MB);  // 8 MB -> 38 MB

    int use_pre = (ws_size >= 64 * MB) ? 1 : 0;
    short *qb = 0, *kb2 = 0, *vb2 = 0, *Wob = 0;
    if (use_pre) {
        qb  = (short*)(ws + 38 * MB);  // 8 MB
        kb2 = (short*)(ws + 46 * MB);  // 8 MB
        vb2 = (short*)(ws + 54 * MB);  // 8 MB
        Wob = (short*)(ws + 62 * MB);  // 2 MB -> 64 MB
    }

    int wn = HEADNUM * DHEAD * DMODEL;  // 1048576
    wtrans_kernel<<<dim3((wn + 255) / 256), 256, 0, stream>>>(Wq, WqT);
    wtrans_kernel<<<dim3((wn + 255) / 256), 256, 0, stream>>>(Wk, WkT);
    wtrans_kernel<<<dim3((wn + 255) / 256), 256, 0, stream>>>(Wv, WvT);

    if (use_pre) {
        int n8a = SEQ * DMODEL / 8;     // 524288
        int n8w = DMODEL * DMODEL / 8;  // 131072
        cast_bf16_kernel<<<dim3((n8a + 255) / 256), 256, 0, stream>>>(q, qb, n8a);
        cast_bf16_kernel<<<dim3((n8a + 255) / 256), 256, 0, stream>>>(k, kb2, n8a);
        cast_bf16_kernel<<<dim3((n8a + 255) / 256), 256, 0, stream>>>(v, vb2, n8a);
        cast_bf16_kernel<<<dim3((n8w + 255) / 256), 256, 0, stream>>>(Wo, Wob, n8w);
    }

    proj_kernel<<<dim3(SEQ / 64, HEADNUM, 3), 256, 0, stream>>>(
        q, k, v, qb, kb2, vb2, WqT, WkT, WvT, qh, kh, vt, use_pre);

    attn_kernel<<<dim3(SEQ / 64 * HEADNUM), 256, 0, stream>>>(qh, kh, vt, hc);

    ogemm_kernel<<<dim3(SEQ / 64, DMODEL / 64), 256, 0, stream>>>(hc, Wo, Wob, out, use_pre);
}

// Round 3
// 248.708 us; speedup vs baseline: 3.9391x; 2.1278x over previous
//
#include <hip/hip_runtime.h>

#define SEQ 4096
#define DMODEL 1024
#define HEADNUM 16
#define DHEAD 64

typedef __attribute__((ext_vector_type(8))) short short8;
typedef __attribute__((ext_vector_type(4))) float f32x4;

__device__ __forceinline__ short f2bf(float f) {
    unsigned u = __float_as_uint(f);
    u = (u + 0x7fffu + ((u >> 16) & 1u)) >> 16;
    return (short)u;
}

__device__ __forceinline__ short8 cvt8(const float4 a, const float4 b) {
    short8 r;
    r[0] = f2bf(a.x); r[1] = f2bf(a.y); r[2] = f2bf(a.z); r[3] = f2bf(a.w);
    r[4] = f2bf(b.x); r[5] = f2bf(b.y); r[6] = f2bf(b.z); r[7] = f2bf(b.w);
    return r;
}

__device__ __forceinline__ unsigned cvtpk_bf16(float lo, float hi) {
    unsigned r;
    asm("v_cvt_pk_bf16_f32 %0, %1, %2" : "=v"(r) : "v"(lo), "v"(hi));
    return r;
}

__device__ __forceinline__ void gld16(const void* g, void* l) {
    __builtin_amdgcn_global_load_lds(
        (const __attribute__((address_space(1))) void*)g,
        (__attribute__((address_space(3))) void*)l, 16, 0, 0);
}

// ---------------------------------------------------------------------------
// Coalesced transpose+cast: W [H][DMODEL][DHEAD] f32 -> WT [H][DHEAD][DMODEL] bf16
// grid (DMODEL/64, HEADNUM)
// ---------------------------------------------------------------------------
__global__ __launch_bounds__(256) void wtrans_kernel(const float* __restrict__ W,
                                                     short* __restrict__ WT) {
    int h = blockIdx.y, d0 = blockIdx.x * 64;
    int tid = threadIdx.x;
    int c = tid & 63, r4 = tid >> 6;
    __shared__ short tl[64][66];
#pragma unroll
    for (int i = 0; i < 16; ++i) {
        int d = i * 4 + r4;
        tl[c][d] = f2bf(W[((size_t)h * DMODEL + d0 + d) * DHEAD + c]);
    }
    __syncthreads();
#pragma unroll
    for (int i = 0; i < 16; ++i) {
        int n = i * 4 + r4;
        WT[((size_t)h * DHEAD + n) * DMODEL + d0 + c] = tl[n][c];
    }
}

// ---------------------------------------------------------------------------
// Cast f32 -> bf16, 8/thread
// ---------------------------------------------------------------------------
__global__ __launch_bounds__(256) void cast_bf16_kernel(const float* __restrict__ in,
                                                        short* __restrict__ out, int n8) {
    int i = blockIdx.x * 256 + threadIdx.x;
    if (i >= n8) return;
    const float4* p = (const float4*)(in + i * 8);
    *(short8*)(out + i * 8) = cvt8(p[0], p[1]);
}

// ---------------------------------------------------------------------------
// GEMM: C[4096,1024] = A[4096,1024](bf16) @ B[1024,1024](bf16, row=[n][k])^T
// BM=64, BN=128, BK=64, 4 waves (2x2), double-buffered LDS via global_load_lds,
// T2 swizzle. mode 0: bf16 C[m][n]; mode 1: bf16 C^T at outb[n*4096+m] (vt);
// mode 2: f32 C[m][n].
// grid 512 = 64 m-tiles x 8 n-tiles, XCD-swizzled.
// ---------------------------------------------------------------------------
__global__ __launch_bounds__(256) void gemm_kernel(
    const short* __restrict__ A, const short* __restrict__ Bw,
    short* __restrict__ outb, float* __restrict__ outf, int mode) {
    int b = blockIdx.x;
    int wgid = (b & 7) * 64 + (b >> 3);
    int bi = wgid >> 3;
    int ni = wgid & 7;
    int i0 = bi * 64, j0 = ni * 128;

    int tid = threadIdx.x;
    int lane = tid & 63;
    int wv = tid >> 6;
    int l15 = lane & 15;
    int g = lane >> 4;
    int wm = wv >> 1, wn = wv & 1;

    __shared__ char glds[2][24576];  // A: 8 KB (64x128B), B: 16 KB (128x128B)

    int ja0 = tid * 16, ja1 = ja0 + 4096;
    int sa0 = (ja0 >> 7) * 2048 + ((ja0 & 127) ^ (((ja0 >> 7) & 7) << 4));
    int sa1 = (ja1 >> 7) * 2048 + ((ja1 & 127) ^ (((ja1 >> 7) & 7) << 4));
    int jb0 = tid * 16, jb1 = jb0 + 4096, jb2 = jb0 + 8192, jb3 = jb0 + 12288;
    int sb0 = (jb0 >> 7) * 2048 + ((jb0 & 127) ^ (((jb0 >> 7) & 7) << 4));
    int sb1 = (jb1 >> 7) * 2048 + ((jb1 & 127) ^ (((jb1 >> 7) & 7) << 4));
    int sb2 = (jb2 >> 7) * 2048 + ((jb2 & 127) ^ (((jb2 >> 7) & 7) << 4));
    int sb3 = (jb3 >> 7) * 2048 + ((jb3 & 127) ^ (((jb3 >> 7) & 7) << 4));

    const char* Ab = (const char*)A + (size_t)i0 * 2048;
    const char* Bb = (const char*)Bw + (size_t)j0 * 2048;

#define GSTAGE(bi_, kt_)                        \
    {                                           \
        char* la_ = glds[bi_];                  \
        char* lb_ = glds[bi_] + 8192;           \
        const char* As = Ab + (kt_) * 128;      \
        const char* Bs = Bb + (kt_) * 128;      \
        gld16(As + sa0, la_ + ja0);             \
        gld16(As + sa1, la_ + ja1);             \
        gld16(Bs + sb0, lb_ + jb0);             \
        gld16(Bs + sb1, lb_ + jb1);             \
        gld16(Bs + sb2, lb_ + jb2);             \
        gld16(Bs + sb3, lb_ + jb3);             \
    }

    f32x4 acc[2][4];
#pragma unroll
    for (int mm = 0; mm < 2; ++mm)
#pragma unroll
        for (int nn = 0; nn < 4; ++nn) acc[mm][nn] = (f32x4){0.f, 0.f, 0.f, 0.f};

    GSTAGE(0, 0);
    int cur = 0;
    for (int kt = 0; kt < 16; ++kt) {
        __syncthreads();  // drains vmcnt: stage(kt) landed
        if (kt < 15) GSTAGE(cur ^ 1, kt + 1);
        const char* la = glds[cur];
        const char* lb = glds[cur] + 8192;
#pragma unroll
        for (int kc = 0; kc < 2; ++kc) {
            short8 af[2], bf4[4];
#pragma unroll
            for (int mm = 0; mm < 2; ++mm) {
                int ra = wm * 32 + mm * 16 + l15;
                af[mm] = *(const short8*)(la + ra * 128 + ((kc * 64 + g * 16) ^ ((ra & 7) << 4)));
            }
#pragma unroll
            for (int nn = 0; nn < 4; ++nn) {
                int rb = wn * 64 + nn * 16 + l15;
                bf4[nn] = *(const short8*)(lb + rb * 128 + ((kc * 64 + g * 16) ^ ((rb & 7) << 4)));
            }
#pragma unroll
            for (int mm = 0; mm < 2; ++mm)
#pragma unroll
                for (int nn = 0; nn < 4; ++nn)
                    acc[mm][nn] = __builtin_amdgcn_mfma_f32_16x16x32_bf16(af[mm], bf4[nn], acc[mm][nn], 0, 0, 0);
        }
        cur ^= 1;
    }
#undef GSTAGE

#pragma unroll
    for (int mm = 0; mm < 2; ++mm)
#pragma unroll
        for (int nn = 0; nn < 4; ++nn)
#pragma unroll
            for (int r = 0; r < 4; ++r) {
                int mg = i0 + wm * 32 + mm * 16 + 4 * g + r;
                int ng = j0 + wn * 64 + nn * 16 + l15;
                float val = acc[mm][nn][r];
                if (mode == 0)      outb[(size_t)mg * 1024 + ng] = f2bf(val);
                else if (mode == 1) outb[(size_t)ng * 4096 + mg] = f2bf(val);
                else                outf[(size_t)mg * 1024 + ng] = val;
            }
}

// ---------------------------------------------------------------------------
// Flash attention, swapped-QK^T softmax. qh/kh flat [s][1024] bf16 (head cols
// h*64..), vt [h*64+dv][s] bf16, out hc flat [s][1024] bf16.
// Per wave: 16 q-rows; lane owns q=lane&15, k=16t+4g+r in-lane.
// ---------------------------------------------------------------------------
__global__ __launch_bounds__(256) void attn_kernel(
    const short* __restrict__ qh, const short* __restrict__ kh,
    const short* __restrict__ vt, short* __restrict__ hc) {
    int wg = ((blockIdx.x & 7) << 7) | (blockIdx.x >> 3);
    int h = wg >> 6;
    int qblk = wg & 63;

    const char* kbase = (const char*)kh + (size_t)h * 128;
    const short* vt_h = vt + (size_t)h * DHEAD * SEQ;

    int tid = threadIdx.x;
    int lane = tid & 63;
    int wv = tid >> 6;
    int l15 = lane & 15;
    int g = lane >> 4;
    int qbase = qblk * 64 + wv * 16;

    __shared__ short kbuf[2][4096];
    __shared__ short vbuf[2][4096];
    __shared__ short p_lds[4][1024];

    const short* qp = qh + (size_t)(qbase + l15) * DMODEL + h * 64 + g * 8;
    short8 aq0 = *(const short8*)(qp);
    short8 aq1 = *(const short8*)(qp + 32);

    int j0 = tid * 16;
    int j1 = j0 + 4096;
    int row0 = j0 >> 7, row1 = j1 >> 7;
    int cc0 = (j0 & 127) ^ ((row0 & 7) << 4);
    int cc1 = (j1 & 127) ^ ((row1 & 7) << 4);
    int ksrc0 = row0 * 2048 + cc0, ksrc1 = row1 * 2048 + cc1;
    int vsrc0 = row0 * (SEQ * 2) + cc0, vsrc1 = row1 * (SEQ * 2) + cc1;

#define STAGE(bi, kb)                                                          \
    {                                                                          \
        gld16(kbase + (size_t)(kb) * 2048 + ksrc0, (char*)kbuf[bi] + j0);      \
        gld16(kbase + (size_t)(kb) * 2048 + ksrc1, (char*)kbuf[bi] + j1);      \
        gld16((const char*)vt_h + (kb) * 2 + vsrc0, (char*)vbuf[bi] + j0);     \
        gld16((const char*)vt_h + (kb) * 2 + vsrc1, (char*)vbuf[bi] + j1);     \
    }

    float mreg = -1e30f, lsreg = 0.f;
    f32x4 oacc[4];
#pragma unroll
    for (int t = 0; t < 4; ++t) oacc[t] = (f32x4){0.f, 0.f, 0.f, 0.f};

    STAGE(0, 0);
    int cur = 0;
    const float C1 = 0.18033688f;   // 0.125 * log2(e)
    const float L2E = 1.44269504f;
    int wsw = (l15 & 7) << 4;

    for (int kb = 0; kb < SEQ; kb += 64) {
        __syncthreads();
        if (kb + 64 < SEQ) STAGE(cur ^ 1, kb + 64);

        const char* kp = (const char*)kbuf[cur];
        const char* vp = (const char*)vbuf[cur];

        // ---- S^T tile: sacc[t] holds rows k=16t+4g+r, col q=l15 ----
        f32x4 sacc[4];
#pragma unroll
        for (int t = 0; t < 4; ++t) {
            int row = t * 16 + l15;
            int sw = (row & 7) << 4;
            short8 bk0 = *(const short8*)(kp + row * 128 + ((g * 16) ^ sw));
            short8 bk1 = *(const short8*)(kp + row * 128 + ((64 + g * 16) ^ sw));
            f32x4 s = (f32x4){0.f, 0.f, 0.f, 0.f};
            s = __builtin_amdgcn_mfma_f32_16x16x32_bf16(bk0, aq0, s, 0, 0, 0);
            s = __builtin_amdgcn_mfma_f32_16x16x32_bf16(bk1, aq1, s, 0, 0, 0);
            sacc[t] = s;
        }

        // ---- softmax: in-lane max over 16, 2 cross-group shfls ----
        float mx0 = fmaxf(fmaxf(sacc[0][0], sacc[0][1]), fmaxf(sacc[0][2], sacc[0][3]));
        float mx1 = fmaxf(fmaxf(sacc[1][0], sacc[1][1]), fmaxf(sacc[1][2], sacc[1][3]));
        float mx2 = fmaxf(fmaxf(sacc[2][0], sacc[2][1]), fmaxf(sacc[2][2], sacc[2][3]));
        float mx3 = fmaxf(fmaxf(sacc[3][0], sacc[3][1]), fmaxf(sacc[3][2], sacc[3][3]));
        float mx = fmaxf(fmaxf(mx0, mx1), fmaxf(mx2, mx3));
        mx = fmaxf(mx, __shfl_xor(mx, 16));
        mx = fmaxf(mx, __shfl_xor(mx, 32));
        float pm = mx * 0.125f;

        if (__any(pm > mreg + 8.f)) {  // T13 defer-max
            float nm = fmaxf(mreg, pm);
            float al = exp2f((mreg - nm) * L2E);
            mreg = nm;
            int sl = 20 * g;
            float al0 = __shfl(al, sl);
            float al1 = __shfl(al, sl + 1);
            float al2 = __shfl(al, sl + 2);
            float al3 = __shfl(al, sl + 3);
            lsreg *= al;
#pragma unroll
            for (int t = 0; t < 4; ++t) {
                oacc[t][0] *= al0; oacc[t][1] *= al1;
                oacc[t][2] *= al2; oacc[t][3] *= al3;
            }
        }

        float mL = mreg * L2E;
        float sum = 0.f;
        unsigned pw[4][2];
#pragma unroll
        for (int t = 0; t < 4; ++t) {
            float e0 = exp2f(fmaf(sacc[t][0], C1, -mL));
            float e1 = exp2f(fmaf(sacc[t][1], C1, -mL));
            float e2 = exp2f(fmaf(sacc[t][2], C1, -mL));
            float e3 = exp2f(fmaf(sacc[t][3], C1, -mL));
            sum += (e0 + e1) + (e2 + e3);
            pw[t][0] = cvtpk_bf16(e0, e1);
            pw[t][1] = cvtpk_bf16(e2, e3);
        }
        sum += __shfl_xor(sum, 16);
        sum += __shfl_xor(sum, 32);
        lsreg += sum;

        // ---- P row (q=l15) packed pairs -> wave-private swizzled LDS ----
        char* pwb = (char*)p_lds[wv] + l15 * 128;
#pragma unroll
        for (int t = 0; t < 4; ++t) {
            *(unsigned*)(pwb + ((t * 32 + g * 8) ^ wsw)) = pw[t][0];
            *(unsigned*)(pwb + ((t * 32 + g * 8 + 4) ^ wsw)) = pw[t][1];
        }
        asm volatile("s_waitcnt lgkmcnt(0)" ::: "memory");
        __builtin_amdgcn_sched_barrier(0);

        const char* pr = (const char*)p_lds[wv] + l15 * 128;
        short8 pa0 = *(const short8*)(pr + ((g * 16) ^ wsw));
        short8 pa1 = *(const short8*)(pr + ((64 + g * 16) ^ wsw));

        // ---- O += P V ----
#pragma unroll
        for (int t = 0; t < 4; ++t) {
            int row = t * 16 + l15;
            int sw = (row & 7) << 4;
            short8 bv0 = *(const short8*)(vp + row * 128 + ((g * 16) ^ sw));
            short8 bv1 = *(const short8*)(vp + row * 128 + ((64 + g * 16) ^ sw));
            oacc[t] = __builtin_amdgcn_mfma_f32_16x16x32_bf16(pa0, bv0, oacc[t], 0, 0, 0);
            oacc[t] = __builtin_amdgcn_mfma_f32_16x16x32_bf16(pa1, bv1, oacc[t], 0, 0, 0);
        }
        cur ^= 1;
    }
#undef STAGE

    // ---- normalize (ls redistributed to q=4g+r) + write head_cat ----
    int sl = 20 * g;
    float ls0 = __shfl(lsreg, sl);
    float ls1 = __shfl(lsreg, sl + 1);
    float ls2 = __shfl(lsreg, sl + 2);
    float ls3 = __shfl(lsreg, sl + 3);
    float i0v = 1.f / ls0, i1v = 1.f / ls1, i2v = 1.f / ls2, i3v = 1.f / ls3;
#pragma unroll
    for (int t = 0; t < 4; ++t) {
        int col = h * 64 + t * 16 + l15;
        hc[(size_t)(qbase + 4 * g + 0) * DMODEL + col] = f2bf(oacc[t][0] * i0v);
        hc[(size_t)(qbase + 4 * g + 1) * DMODEL + col] = f2bf(oacc[t][1] * i1v);
        hc[(size_t)(qbase + 4 * g + 2) * DMODEL + col] = f2bf(oacc[t][2] * i2v);
        hc[(size_t)(qbase + 4 * g + 3) * DMODEL + col] = f2bf(oacc[t][3] * i3v);
    }
}

// ---------------------------------------------------------------------------
extern "C" void kernel_launch(void* const* d_in, const int* in_sizes, int n_in,
                              void* d_out, int out_size, void* d_ws, size_t ws_size,
                              hipStream_t stream) {
    const float* q  = (const float*)d_in[0];
    const float* k  = (const float*)d_in[1];
    const float* v  = (const float*)d_in[2];
    const float* Wq = (const float*)d_in[3];
    const float* Wk = (const float*)d_in[4];
    const float* Wv = (const float*)d_in[5];
    const float* Wo = (const float*)d_in[6];
    float* out = (float*)d_out;

    char* ws = (char*)d_ws;
    const size_t MB = 1u << 20;
    short* WqT  = (short*)(ws + 0 * MB);   // 2 MB (reused as Wob after proj)
    short* WkT  = (short*)(ws + 2 * MB);   // 2 MB
    short* WvT  = (short*)(ws + 4 * MB);   // 2 MB
    short* qh   = (short*)(ws + 6 * MB);   // 8 MB
    short* kh   = (short*)(ws + 14 * MB);  // 8 MB
    short* vt   = (short*)(ws + 22 * MB);  // 8 MB
    short* hcqb = (short*)(ws + 30 * MB);  // 8 MB: qb during proj, hc after attn
    short* Wob  = WqT;
    // bf16 k/v casts live in d_out (dead until final GEMM fully rewrites it)
    short* kb = (short*)d_out;                    // 8 MB
    short* vb = (short*)d_out + SEQ * DMODEL;     // 8 MB

    wtrans_kernel<<<dim3(DMODEL / 64, HEADNUM), 256, 0, stream>>>(Wq, WqT);
    wtrans_kernel<<<dim3(DMODEL / 64, HEADNUM), 256, 0, stream>>>(Wk, WkT);
    wtrans_kernel<<<dim3(DMODEL / 64, HEADNUM), 256, 0, stream>>>(Wv, WvT);

    int n8a = SEQ * DMODEL / 8;
    cast_bf16_kernel<<<dim3(n8a / 256), 256, 0, stream>>>(q, hcqb, n8a);
    cast_bf16_kernel<<<dim3(n8a / 256), 256, 0, stream>>>(k, kb, n8a);
    cast_bf16_kernel<<<dim3(n8a / 256), 256, 0, stream>>>(v, vb, n8a);

    gemm_kernel<<<dim3(512), 256, 0, stream>>>(hcqb, WqT, qh, 0, 0);
    gemm_kernel<<<dim3(512), 256, 0, stream>>>(kb, WkT, kh, 0, 0);
    gemm_kernel<<<dim3(512), 256, 0, stream>>>(vb, WvT, vt, 0, 1);

    int n8w = DMODEL * DMODEL / 8;
    cast_bf16_kernel<<<dim3(n8w / 256), 256, 0, stream>>>(Wo, Wob, n8w);

    attn_kernel<<<dim3(SEQ / 64 * HEADNUM), 256, 0, stream>>>(qh, kh, vt, hcqb);

    gemm_kernel<<<dim3(512), 256, 0, stream>>>(hcqb, Wob, 0, out, 2);
}

// Round 4
// 238.060 us; speedup vs baseline: 4.1153x; 1.0447x over previous
//
#include <hip/hip_runtime.h>

#define SEQ 4096
#define DMODEL 1024
#define HEADNUM 16
#define DHEAD 64

typedef __attribute__((ext_vector_type(8))) short short8;
typedef __attribute__((ext_vector_type(4))) float f32x4;
typedef __attribute__((ext_vector_type(2))) float f32x2;
typedef __attribute__((ext_vector_type(4))) int i32x4;
typedef __attribute__((ext_vector_type(2))) int i32x2;

__device__ __forceinline__ short f2bf(float f) {
    unsigned u = __float_as_uint(f);
    u = (u + 0x7fffu + ((u >> 16) & 1u)) >> 16;
    return (short)u;
}

__device__ __forceinline__ float bf2f(short s) {
    return __uint_as_float(((unsigned)(unsigned short)s) << 16);
}

__device__ __forceinline__ short8 cvt8(const float4 a, const float4 b) {
    short8 r;
    r[0] = f2bf(a.x); r[1] = f2bf(a.y); r[2] = f2bf(a.z); r[3] = f2bf(a.w);
    r[4] = f2bf(b.x); r[5] = f2bf(b.y); r[6] = f2bf(b.z); r[7] = f2bf(b.w);
    return r;
}

__device__ __forceinline__ int cvtpk_bf16(float lo, float hi) {
    int r;
    asm("v_cvt_pk_bf16_f32 %0, %1, %2" : "=v"(r) : "v"(lo), "v"(hi));
    return r;
}

__device__ __forceinline__ void gld16(const void* g, void* l) {
    __builtin_amdgcn_global_load_lds(
        (const __attribute__((address_space(1))) void*)g,
        (__attribute__((address_space(3))) void*)l, 16, 0, 0);
}

// ---------------------------------------------------------------------------
// Coalesced transpose+cast: W [H][DMODEL][DHEAD] f32 -> WT [H][DHEAD][DMODEL] bf16
// ---------------------------------------------------------------------------
__global__ __launch_bounds__(256) void wtrans_kernel(const float* __restrict__ W,
                                                     short* __restrict__ WT) {
    int h = blockIdx.y, d0 = blockIdx.x * 64;
    int tid = threadIdx.x;
    int c = tid & 63, r4 = tid >> 6;
    __shared__ short tl[64][66];
#pragma unroll
    for (int i = 0; i < 16; ++i) {
        int d = i * 4 + r4;
        tl[c][d] = f2bf(W[((size_t)h * DMODEL + d0 + d) * DHEAD + c]);
    }
    __syncthreads();
#pragma unroll
    for (int i = 0; i < 16; ++i) {
        int n = i * 4 + r4;
        WT[((size_t)h * DHEAD + n) * DMODEL + d0 + c] = tl[n][c];
    }
}

// ---------------------------------------------------------------------------
__global__ __launch_bounds__(256) void cast_bf16_kernel(const float* __restrict__ in,
                                                        short* __restrict__ out, int n8) {
    int i = blockIdx.x * 256 + threadIdx.x;
    if (i >= n8) return;
    const float4* p = (const float4*)(in + i * 8);
    *(short8*)(out + i * 8) = cvt8(p[0], p[1]);
}

// ---------------------------------------------------------------------------
// GEMM: C[4096,1024] = A[4096,1024](bf16) @ B[1024,1024](bf16 [n][k])^T
// BM=64, BN=128, BK=64, dbuf LDS, T2 swizzle. mode 0: bf16 C; mode 1: bf16 C^T;
// mode 2: f32 C. grid 512, XCD-swizzled.
// ---------------------------------------------------------------------------
__global__ __launch_bounds__(256) void gemm_kernel(
    const short* __restrict__ A, const short* __restrict__ Bw,
    short* __restrict__ outb, float* __restrict__ outf, int mode) {
    int b = blockIdx.x;
    int wgid = (b & 7) * 64 + (b >> 3);
    int bi = wgid >> 3;
    int ni = wgid & 7;
    int i0 = bi * 64, j0 = ni * 128;

    int tid = threadIdx.x;
    int lane = tid & 63;
    int wv = tid >> 6;
    int l15 = lane & 15;
    int g = lane >> 4;
    int wm = wv >> 1, wn = wv & 1;

    __shared__ char glds[2][24576];

    int ja0 = tid * 16, ja1 = ja0 + 4096;
    int sa0 = (ja0 >> 7) * 2048 + ((ja0 & 127) ^ (((ja0 >> 7) & 7) << 4));
    int sa1 = (ja1 >> 7) * 2048 + ((ja1 & 127) ^ (((ja1 >> 7) & 7) << 4));
    int jb0 = tid * 16, jb1 = jb0 + 4096, jb2 = jb0 + 8192, jb3 = jb0 + 12288;
    int sb0 = (jb0 >> 7) * 2048 + ((jb0 & 127) ^ (((jb0 >> 7) & 7) << 4));
    int sb1 = (jb1 >> 7) * 2048 + ((jb1 & 127) ^ (((jb1 >> 7) & 7) << 4));
    int sb2 = (jb2 >> 7) * 2048 + ((jb2 & 127) ^ (((jb2 >> 7) & 7) << 4));
    int sb3 = (jb3 >> 7) * 2048 + ((jb3 & 127) ^ (((jb3 >> 7) & 7) << 4));

    const char* Ab = (const char*)A + (size_t)i0 * 2048;
    const char* Bb = (const char*)Bw + (size_t)j0 * 2048;

#define GSTAGE(bi_, kt_)                        \
    {                                           \
        char* la_ = glds[bi_];                  \
        char* lb_ = glds[bi_] + 8192;           \
        const char* As = Ab + (kt_) * 128;      \
        const char* Bs = Bb + (kt_) * 128;      \
        gld16(As + sa0, la_ + ja0);             \
        gld16(As + sa1, la_ + ja1);             \
        gld16(Bs + sb0, lb_ + jb0);             \
        gld16(Bs + sb1, lb_ + jb1);             \
        gld16(Bs + sb2, lb_ + jb2);             \
        gld16(Bs + sb3, lb_ + jb3);             \
    }

    f32x4 acc[2][4];
#pragma unroll
    for (int mm = 0; mm < 2; ++mm)
#pragma unroll
        for (int nn = 0; nn < 4; ++nn) acc[mm][nn] = (f32x4){0.f, 0.f, 0.f, 0.f};

    GSTAGE(0, 0);
    int cur = 0;
    for (int kt = 0; kt < 16; ++kt) {
        __syncthreads();
        if (kt < 15) GSTAGE(cur ^ 1, kt + 1);
        const char* la = glds[cur];
        const char* lb = glds[cur] + 8192;
#pragma unroll
        for (int kc = 0; kc < 2; ++kc) {
            short8 af[2], bf4[4];
#pragma unroll
            for (int mm = 0; mm < 2; ++mm) {
                int ra = wm * 32 + mm * 16 + l15;
                af[mm] = *(const short8*)(la + ra * 128 + ((kc * 64 + g * 16) ^ ((ra & 7) << 4)));
            }
#pragma unroll
            for (int nn = 0; nn < 4; ++nn) {
                int rb = wn * 64 + nn * 16 + l15;
                bf4[nn] = *(const short8*)(lb + rb * 128 + ((kc * 64 + g * 16) ^ ((rb & 7) << 4)));
            }
#pragma unroll
            for (int mm = 0; mm < 2; ++mm)
#pragma unroll
                for (int nn = 0; nn < 4; ++nn)
                    acc[mm][nn] = __builtin_amdgcn_mfma_f32_16x16x32_bf16(af[mm], bf4[nn], acc[mm][nn], 0, 0, 0);
        }
        cur ^= 1;
    }
#undef GSTAGE

#pragma unroll
    for (int mm = 0; mm < 2; ++mm)
#pragma unroll
        for (int nn = 0; nn < 4; ++nn)
#pragma unroll
            for (int r = 0; r < 4; ++r) {
                int mg = i0 + wm * 32 + mm * 16 + 4 * g + r;
                int ng = j0 + wn * 64 + nn * 16 + l15;
                float val = acc[mm][nn][r];
                if (mode == 0)      outb[(size_t)mg * 1024 + ng] = f2bf(val);
                else if (mode == 1) outb[(size_t)ng * 4096 + mg] = f2bf(val);
                else                outf[(size_t)mg * 1024 + ng] = val;
            }
}

// ---------------------------------------------------------------------------
// Flash attention, split-KV x2, O^T orientation, bpermute P-redistribution.
// Block: 4 waves x 32 q = 128 q rows, kv range = half*2048..+2048, KVBLK=32.
// Writes unnormalized O partials (bf16) to po[half][s][1024] and (m,l) to
// ml[half][h][s][2].
// ---------------------------------------------------------------------------
__global__ __launch_bounds__(256, 4) void attn_kernel(
    const short* __restrict__ qh, const short* __restrict__ kh,
    const short* __restrict__ vt, short* __restrict__ po, float* __restrict__ ml) {
    int b = blockIdx.x;
    int wg = ((b & 7) << 7) | (b >> 3);  // XCD chunks of 128 wg = 2 heads
    int h = wg >> 6;
    int rem = wg & 63;
    int half = rem >> 5;
    int qb = rem & 31;

    int tid = threadIdx.x;
    int lane = tid & 63;
    int wv = tid >> 6;
    int l15 = lane & 15;
    int g = lane >> 4;
    int qbase = qb * 128 + wv * 32;
    int kv0 = half * 2048;

    const char* kbase = (const char*)kh + h * 128;
    const char* vbase = (const char*)vt + (size_t)h * 64 * 8192;

    __shared__ char kbuf[2][4096];
    __shared__ char vbuf[2][4096];

    // Q B-fragments: lane(l15=q-col, g): d = c*32 + g*8 + j
    short8 bq[2][2];
#pragma unroll
    for (int qg = 0; qg < 2; ++qg) {
        const short* qp = qh + (size_t)(qbase + qg * 16 + l15) * 1024 + h * 64 + g * 8;
        bq[qg][0] = *(const short8*)(qp);
        bq[qg][1] = *(const short8*)(qp + 32);
    }

    // staging offsets (K pre-swizzled source, V linear)
    int rk = tid >> 3, kcol = (tid & 7) * 16;
    int koff = rk * 2048 + (kcol ^ ((rk & 7) << 4));
    int rv = tid >> 2, vcol = (tid & 3) * 16;
    int voff = rv * 8192 + vcol;
    int ldst = tid * 16;

#define STAGE(bi, kvg)                                                \
    {                                                                 \
        gld16(kbase + (size_t)(kvg) * 2048 + koff, kbuf[bi] + ldst);  \
        gld16(vbase + (size_t)(kvg) * 2 + voff, vbuf[bi] + ldst);     \
    }

    float mreg[2] = {4.f, 4.f}, lsum[2] = {0.f, 0.f};
    f32x4 oacc[2][4];
#pragma unroll
    for (int qg = 0; qg < 2; ++qg)
#pragma unroll
        for (int t4 = 0; t4 < 4; ++t4) oacc[qg][t4] = (f32x4){0.f, 0.f, 0.f, 0.f};

    int lA4 = (l15 + ((g & 1) << 5)) * 4;
    int lB4 = lA4 + 64;
    int swl = (l15 & 7) << 4;

    STAGE(0, kv0);
    int cur = 0;
    const float C1 = 0.18033688f;   // 0.125 * log2(e)
    const float L2E = 1.44269504f;

    for (int t = 0; t < 64; ++t) {
        __syncthreads();  // implicit vmcnt(0): stage(t) landed
        if (t < 63) STAGE(cur ^ 1, kv0 + (t + 1) * 32);
        const char* kp = kbuf[cur];
        const char* vp = vbuf[cur];

        // ---- K A-fragments + S^T = mfma(K, Q) ----
        short8 ak[2][2];
#pragma unroll
        for (int tt = 0; tt < 2; ++tt) {
            int rbase = (tt * 16 + l15) * 128;
            ak[tt][0] = *(const short8*)(kp + rbase + ((g * 16) ^ swl));
            ak[tt][1] = *(const short8*)(kp + rbase + ((64 + g * 16) ^ swl));
        }
        f32x4 sacc[2][2];
#pragma unroll
        for (int qg = 0; qg < 2; ++qg)
#pragma unroll
            for (int tt = 0; tt < 2; ++tt) {
                f32x4 s = (f32x4){0.f, 0.f, 0.f, 0.f};
                s = __builtin_amdgcn_mfma_f32_16x16x32_bf16(ak[tt][0], bq[qg][0], s, 0, 0, 0);
                s = __builtin_amdgcn_mfma_f32_16x16x32_bf16(ak[tt][1], bq[qg][1], s, 0, 0, 0);
                sacc[qg][tt] = s;
            }

        // ---- deferred online softmax (no cross-lane on the hot path) ----
        float pm[2];
#pragma unroll
        for (int qg = 0; qg < 2; ++qg) {
            float a0 = fmaxf(fmaxf(sacc[qg][0][0], sacc[qg][0][1]),
                             fmaxf(sacc[qg][0][2], sacc[qg][0][3]));
            float a1 = fmaxf(fmaxf(sacc[qg][1][0], sacc[qg][1][1]),
                             fmaxf(sacc[qg][1][2], sacc[qg][1][3]));
            pm[qg] = fmaxf(a0, a1) * 0.125f;
        }
        if (__any(fmaxf(pm[0] - mreg[0], pm[1] - mreg[1]) > 8.f)) {
#pragma unroll
            for (int qg = 0; qg < 2; ++qg) {
                float pmq = pm[qg];
                pmq = fmaxf(pmq, __shfl_xor(pmq, 16));
                pmq = fmaxf(pmq, __shfl_xor(pmq, 32));
                float nm = fmaxf(mreg[qg], pmq);
                float al = exp2f((mreg[qg] - nm) * L2E);
                mreg[qg] = nm;
                lsum[qg] *= al;
#pragma unroll
                for (int t4 = 0; t4 < 4; ++t4)
#pragma unroll
                    for (int r = 0; r < 4; ++r) oacc[qg][t4][r] *= al;
            }
        }

        unsigned pw[2][2][2];
#pragma unroll
        for (int qg = 0; qg < 2; ++qg) {
            float mL = mreg[qg] * L2E;
            float psum = 0.f;
#pragma unroll
            for (int tt = 0; tt < 2; ++tt) {
                float e0 = exp2f(fmaf(sacc[qg][tt][0], C1, -mL));
                float e1 = exp2f(fmaf(sacc[qg][tt][1], C1, -mL));
                float e2 = exp2f(fmaf(sacc[qg][tt][2], C1, -mL));
                float e3 = exp2f(fmaf(sacc[qg][tt][3], C1, -mL));
                psum += (e0 + e1) + (e2 + e3);
                pw[qg][tt][0] = (unsigned)cvtpk_bf16(e0, e1);
                pw[qg][tt][1] = (unsigned)cvtpk_bf16(e2, e3);
            }
            lsum[qg] += psum;
        }

        // ---- P^T D-layout -> B-fragment via ds_bpermute ----
        short8 pb[2];
#pragma unroll
        for (int qg = 0; qg < 2; ++qg) {
            int a00 = __builtin_amdgcn_ds_bpermute(lA4, (int)pw[qg][0][0]);
            int a01 = __builtin_amdgcn_ds_bpermute(lA4, (int)pw[qg][0][1]);
            int a10 = __builtin_amdgcn_ds_bpermute(lA4, (int)pw[qg][1][0]);
            int a11 = __builtin_amdgcn_ds_bpermute(lA4, (int)pw[qg][1][1]);
            int b00 = __builtin_amdgcn_ds_bpermute(lB4, (int)pw[qg][0][0]);
            int b01 = __builtin_amdgcn_ds_bpermute(lB4, (int)pw[qg][0][1]);
            int b10 = __builtin_amdgcn_ds_bpermute(lB4, (int)pw[qg][1][0]);
            int b11 = __builtin_amdgcn_ds_bpermute(lB4, (int)pw[qg][1][1]);
            i32x4 pbv;
            pbv[0] = (g < 2) ? a00 : a10;
            pbv[1] = (g < 2) ? a01 : a11;
            pbv[2] = (g < 2) ? b00 : b10;
            pbv[3] = (g < 2) ? b01 : b11;
            pb[qg] = *(short8*)&pbv;
        }

        // ---- O^T += V^T P^T ----
#pragma unroll
        for (int t4 = 0; t4 < 4; ++t4) {
            short8 av = *(const short8*)(vp + (t4 * 16 + l15) * 64 + g * 16);
            oacc[0][t4] = __builtin_amdgcn_mfma_f32_16x16x32_bf16(av, pb[0], oacc[0][t4], 0, 0, 0);
            oacc[1][t4] = __builtin_amdgcn_mfma_f32_16x16x32_bf16(av, pb[1], oacc[1][t4], 0, 0, 0);
        }
        cur ^= 1;
    }
#undef STAGE

    // ---- epilogue: write unnormalized partials + (m, l) ----
#pragma unroll
    for (int qg = 0; qg < 2; ++qg) {
        float lt = lsum[qg];
        lt += __shfl_xor(lt, 16);
        lt += __shfl_xor(lt, 32);
        int q = qbase + qg * 16 + l15;
        if (g == 0) {
            f32x2 mlv; mlv[0] = mreg[qg]; mlv[1] = lt;
            *(f32x2*)(ml + ((size_t)(half * 16 + h) * 4096 + q) * 2) = mlv;
        }
#pragma unroll
        for (int t4 = 0; t4 < 4; ++t4) {
            i32x2 pk;
            pk[0] = cvtpk_bf16(oacc[qg][t4][0], oacc[qg][t4][1]);
            pk[1] = cvtpk_bf16(oacc[qg][t4][2], oacc[qg][t4][3]);
            *(i32x2*)(po + (size_t)(half * 4096 + q) * 1024 + h * 64 + t4 * 16 + 4 * g) = pk;
        }
    }
}

// ---------------------------------------------------------------------------
// Combine the two split-KV partials: hc = (po0*w0 + po1*w1), w from (m,l).
// ---------------------------------------------------------------------------
__global__ __launch_bounds__(256) void attn_reduce_kernel(
    const short* __restrict__ po, const float* __restrict__ ml,
    short* __restrict__ hc) {
    int idx = blockIdx.x * 256 + threadIdx.x;  // 524288 threads, 8 cols each
    int q = idx >> 7;
    int cb = (idx & 127) * 8;
    int h = cb >> 6;
    f32x2 ml0 = *(const f32x2*)(ml + ((size_t)(h)*4096 + q) * 2);
    f32x2 ml1 = *(const f32x2*)(ml + ((size_t)(16 + h) * 4096 + q) * 2);
    float M = fmaxf(ml0[0], ml1[0]);
    float w0 = exp2f((ml0[0] - M) * 1.44269504f);
    float w1 = exp2f((ml1[0] - M) * 1.44269504f);
    float inv = 1.f / (ml0[1] * w0 + ml1[1] * w1);
    w0 *= inv; w1 *= inv;
    short8 p0 = *(const short8*)(po + (size_t)q * 1024 + cb);
    short8 p1 = *(const short8*)(po + (size_t)(4096 + q) * 1024 + cb);
    short8 r;
#pragma unroll
    for (int j = 0; j < 8; ++j)
        r[j] = f2bf(bf2f(p0[j]) * w0 + bf2f(p1[j]) * w1);
    *(short8*)(hc + (size_t)q * 1024 + cb) = r;
}

// ---------------------------------------------------------------------------
extern "C" void kernel_launch(void* const* d_in, const int* in_sizes, int n_in,
                              void* d_out, int out_size, void* d_ws, size_t ws_size,
                              hipStream_t stream) {
    const float* q  = (const float*)d_in[0];
    const float* k  = (const float*)d_in[1];
    const float* v  = (const float*)d_in[2];
    const float* Wq = (const float*)d_in[3];
    const float* Wk = (const float*)d_in[4];
    const float* Wv = (const float*)d_in[5];
    const float* Wo = (const float*)d_in[6];
    float* out = (float*)d_out;

    char* ws = (char*)d_ws;
    const size_t MB = 1u << 20;
    short* WqT  = (short*)(ws + 0 * MB);   // 2 MB (reused as Wob)
    short* WkT  = (short*)(ws + 2 * MB);   // 2 MB
    short* WvT  = (short*)(ws + 4 * MB);   // 2 MB
    short* qh   = (short*)(ws + 6 * MB);   // 8 MB
    short* kh   = (short*)(ws + 14 * MB);  // 8 MB
    short* vt   = (short*)(ws + 22 * MB);  // 8 MB
    short* hcqb = (short*)(ws + 30 * MB);  // 8 MB: qb during proj, hc after reduce
    float* mlbuf = (float*)(ws + 38 * MB); // 1 MB
    short* Wob  = WqT;
    // bf16 k/v casts and later the attention partials live in d_out (16 MB)
    short* kb = (short*)d_out;
    short* vb = (short*)d_out + SEQ * DMODEL;
    short* po = (short*)d_out;  // [2][4096][1024] bf16 partials (after proj)

    wtrans_kernel<<<dim3(DMODEL / 64, HEADNUM), 256, 0, stream>>>(Wq, WqT);
    wtrans_kernel<<<dim3(DMODEL / 64, HEADNUM), 256, 0, stream>>>(Wk, WkT);
    wtrans_kernel<<<dim3(DMODEL / 64, HEADNUM), 256, 0, stream>>>(Wv, WvT);

    int n8a = SEQ * DMODEL / 8;
    cast_bf16_kernel<<<dim3(n8a / 256), 256, 0, stream>>>(q, hcqb, n8a);
    cast_bf16_kernel<<<dim3(n8a / 256), 256, 0, stream>>>(k, kb, n8a);
    cast_bf16_kernel<<<dim3(n8a / 256), 256, 0, stream>>>(v, vb, n8a);

    gemm_kernel<<<dim3(512), 256, 0, stream>>>(hcqb, WqT, qh, 0, 0);
    gemm_kernel<<<dim3(512), 256, 0, stream>>>(kb, WkT, kh, 0, 0);
    gemm_kernel<<<dim3(512), 256, 0, stream>>>(vb, WvT, vt, 0, 1);

    int n8w = DMODEL * DMODEL / 8;
    cast_bf16_kernel<<<dim3(n8w / 256), 256, 0, stream>>>(Wo, Wob, n8w);

    attn_kernel<<<dim3(1024), 256, 0, stream>>>(qh, kh, vt, po, mlbuf);

    attn_reduce_kernel<<<dim3(2048), 256, 0, stream>>>(po, mlbuf, hcqb);

    gemm_kernel<<<dim3(512), 256, 0, stream>>>(hcqb, Wob, 0, out, 2);
}